// Round 8
// baseline (155.119 us; speedup 1.0000x reference)
//
#include <hip/hip_runtime.h>
#include <math.h>

#define S_NEI 32

// ---------------- transpose 256x256 (WkT[e][f] = Wk[f][e]) ----------------
__global__ __launch_bounds__(256) void transpose256(const float* __restrict__ in,
                                                    float* __restrict__ outT) {
    __shared__ float tile[32][33];
    const int bx = blockIdx.x * 32, by = blockIdx.y * 32;
    const int x = threadIdx.x, y = threadIdx.y;  // 32 x 8
#pragma unroll
    for (int i = 0; i < 32; i += 8)
        tile[y + i][x] = in[(by + y + i) * 256 + bx + x];
    __syncthreads();
#pragma unroll
    for (int i = 0; i < 32; i += 8)
        outT[(bx + y + i) * 256 + by + x] = tile[x][y + i];
}

// ---------------- legacy 8x256 tile GEMM (for tiny precompute GEMMs) -------
template <int KT>
__device__ __forceinline__ void gemm_tile8(const float* __restrict__ A, int row0,
                                           const float* __restrict__ B,
                                           float acc[2][4], float* __restrict__ sA,
                                           float* __restrict__ sB) {
    const int t = threadIdx.x;
    const int tr = t >> 6, tc = t & 63;
    const int r = t >> 5;
    const int k1 = t & 31;
    const size_t arow = (size_t)(row0 + r) * KT;
    for (int kb = 0; kb < KT; kb += 32) {
        sA[k1 * 12 + r] = A[arow + kb + k1];
#pragma unroll
        for (int i = 0; i < 8; ++i) {
            *reinterpret_cast<float4*>(&sB[(i * 4 + tr) * 256 + tc * 4]) =
                *reinterpret_cast<const float4*>(&B[(size_t)(kb + i * 4 + tr) * 256 + tc * 4]);
        }
        __syncthreads();
#pragma unroll
        for (int k = 0; k < 32; ++k) {
            const float2 a2 = *reinterpret_cast<const float2*>(&sA[k * 12 + tr * 2]);
            const float4 b4 = *reinterpret_cast<const float4*>(&sB[k * 256 + tc * 4]);
            acc[0][0] += a2.x * b4.x; acc[0][1] += a2.x * b4.y;
            acc[0][2] += a2.x * b4.z; acc[0][3] += a2.x * b4.w;
            acc[1][0] += a2.y * b4.x; acc[1][1] += a2.y * b4.y;
            acc[1][2] += a2.y * b4.z; acc[1][3] += a2.y * b4.w;
        }
        __syncthreads();
    }
}

// Wqk=Wq@WkT, Wvc=Wv@Wc_top, Wmc=Wm@Wc_bot
__global__ __launch_bounds__(256) void precompute3(const float* __restrict__ Wq,
                                                   const float* __restrict__ Wv,
                                                   const float* __restrict__ Wm,
                                                   const float* __restrict__ Wc,
                                                   const float* __restrict__ WkT,
                                                   float* __restrict__ Wqk,
                                                   float* __restrict__ Wvc,
                                                   float* __restrict__ Wmc) {
    __shared__ float sA[32 * 12];
    __shared__ float sB[32 * 256];
    float acc[2][4] = {};
    const float *Ap, *Bp;
    float* Cp;
    switch (blockIdx.y) {
        case 0: Ap = Wq; Bp = WkT; Cp = Wqk; break;
        case 1: Ap = Wv; Bp = Wc; Cp = Wvc; break;
        default: Ap = Wm; Bp = Wc + 256 * 256; Cp = Wmc; break;
    }
    const int row0 = blockIdx.x * 8;
    gemm_tile8<256>(Ap, row0, Bp, acc, sA, sB);
    const int tr = threadIdx.x >> 6, tc = threadIdx.x & 63;
#pragma unroll
    for (int i = 0; i < 2; ++i) {
        float4 v = make_float4(acc[i][0], acc[i][1], acc[i][2], acc[i][3]);
        *reinterpret_cast<float4*>(&Cp[(row0 + tr * 2 + i) * 256 + tc * 4]) = v;
    }
}

// bqk = bq@WkT ; bfull = bv@Wc_top + bm@Wc_bot + bc  (block per column)
__global__ __launch_bounds__(256) void bias_k(const float* __restrict__ bq,
                                              const float* __restrict__ bv,
                                              const float* __restrict__ bm,
                                              const float* __restrict__ bc,
                                              const float* __restrict__ Wc,
                                              const float* __restrict__ WkT,
                                              float* __restrict__ bqk,
                                              float* __restrict__ bfull) {
    const int c = blockIdx.x;
    const int e = threadIdx.x;
    const int w = e >> 6, l = e & 63;
    float a = bq[e] * WkT[e * 256 + c];
    float v = bv[e] * Wc[e * 256 + c] + bm[e] * Wc[(256 + e) * 256 + c];
    __shared__ float redA[4], redV[4];
#pragma unroll
    for (int off = 32; off; off >>= 1) { a += __shfl_xor(a, off); v += __shfl_xor(v, off); }
    if (l == 0) { redA[w] = a; redV[w] = v; }
    __syncthreads();
    if (e == 0) {
        bqk[c] = redA[0] + redA[1] + redA[2] + redA[3];
        bfull[c] = bc[c] + redV[0] + redV[1] + redV[2] + redV[3];
    }
}

// ---------------- fused per-4-node megakernel, 256 threads, 4 waves --------
// Wave w = K-quarter. Lane owns 4 cols (float4 B-stream). acc[4 rows][4 cols].
// Phase 1: Qk = self(4x256)@Wqk + bqk
// Phase 2: attn+mean, 1 node/wave, online-softmax 8-row chunks
// Phase 3: out = normalize(tanh(AF(4x512)@Wfused + bfull))
// LDS region R0 aliased: sA -> sP -> sAF -> sP. Transposed layout
// SAF4(k) = k*4 + ((k>>3)<<2) keeps float4 row-frags 16B-aligned + bank-spread.

#define SAF4(k) ((k) * 4 + ((((k) >> 3)) << 2))

#define FMA44(a4, b4)                                                       \
    do {                                                                    \
        acc[0][0] += (a4).x * (b4).x; acc[0][1] += (a4).x * (b4).y;         \
        acc[0][2] += (a4).x * (b4).z; acc[0][3] += (a4).x * (b4).w;         \
        acc[1][0] += (a4).y * (b4).x; acc[1][1] += (a4).y * (b4).y;         \
        acc[1][2] += (a4).y * (b4).z; acc[1][3] += (a4).y * (b4).w;         \
        acc[2][0] += (a4).z * (b4).x; acc[2][1] += (a4).z * (b4).y;         \
        acc[2][2] += (a4).z * (b4).z; acc[2][3] += (a4).z * (b4).w;         \
        acc[3][0] += (a4).w * (b4).x; acc[3][1] += (a4).w * (b4).y;         \
        acc[3][2] += (a4).w * (b4).z; acc[3][3] += (a4).w * (b4).w;         \
    } while (0)

__global__ __launch_bounds__(256, 4) void fused4(const float* __restrict__ id2feat,
                                                 const int* __restrict__ nodes,
                                                 const int* __restrict__ neigh_mean,
                                                 const int* __restrict__ neigh_attn,
                                                 const float* __restrict__ Wqk,
                                                 const float* __restrict__ bqk,
                                                 const float* __restrict__ Wfused,
                                                 const float* __restrict__ bfull,
                                                 float* __restrict__ out) {
    // R0 [0, 12480 words*4=49920B? no: 3120 words = 12480 B) aliased sA/sP/sAF
    // sQk 1040 words; sIA 128; sIM 128 ints.
    __shared__ __align__(16) char smem[18112];
    float* R0  = (float*)smem;               // 3120 floats
    float* sQk = (float*)(smem + 12480);     // 1040 floats
    int*   sIA = (int*)(smem + 16640);       // 128
    int*   sIM = (int*)(smem + 17152);       // 128
    // [17664, 18112) pad

    const int t = threadIdx.x;   // 256
    const int w = t >> 6, l = t & 63;
    const int kq = w;
    const int col4 = l * 4;
    const int row0 = blockIdx.x * 4;

    if (t < 128) sIA[t] = neigh_attn[(size_t)row0 * S_NEI + t];
    else sIM[t - 128] = neigh_mean[(size_t)row0 * S_NEI + (t - 128)];

    // stage 4 self rows transposed: wave w reads row w coalesced (1 KB)
    {
        const float4 v = *reinterpret_cast<const float4*>(
            &id2feat[(size_t)nodes[row0 + w] * 256 + col4]);
        R0[SAF4(col4 + 0) + w] = v.x;
        R0[SAF4(col4 + 1) + w] = v.y;
        R0[SAF4(col4 + 2) + w] = v.z;
        R0[SAF4(col4 + 3) + w] = v.w;
    }
    __syncthreads();

    float acc[4][4] = {};

    // ---- phase 1: K-quarter [kq*64, +64), all 256 cols ----
    {
        const float* Bp = Wqk + (size_t)(kq * 64) * 256 + col4;
        float4 bufA[8], bufB[8];
#pragma unroll
        for (int j = 0; j < 8; ++j)
            bufA[j] = *reinterpret_cast<const float4*>(&Bp[(size_t)j * 256]);
        for (int kb = 0; kb < 64; kb += 16) {
#pragma unroll
            for (int j = 0; j < 8; ++j)
                bufB[j] = *reinterpret_cast<const float4*>(&Bp[(size_t)(kb + 8 + j) * 256]);
#pragma unroll
            for (int j = 0; j < 8; ++j) {
                const float4 a4 = *reinterpret_cast<const float4*>(&R0[SAF4(kq * 64 + kb + j)]);
                FMA44(a4, bufA[j]);
            }
            if (kb + 16 < 64) {
#pragma unroll
                for (int j = 0; j < 8; ++j)
                    bufA[j] = *reinterpret_cast<const float4*>(&Bp[(size_t)(kb + 16 + j) * 256]);
            }
#pragma unroll
            for (int j = 0; j < 8; ++j) {
                const float4 a4 =
                    *reinterpret_cast<const float4*>(&R0[SAF4(kq * 64 + kb + 8 + j)]);
                FMA44(a4, bufB[j]);
            }
        }
    }
    __syncthreads();  // sA dead
    if (kq) {
        float* p = R0 + ((kq - 1) * 4) * 260 + col4;
#pragma unroll
        for (int r = 0; r < 4; ++r) {
            p[r * 260 + 0] = acc[r][0]; p[r * 260 + 1] = acc[r][1];
            p[r * 260 + 2] = acc[r][2]; p[r * 260 + 3] = acc[r][3];
        }
    }
    __syncthreads();
    if (kq == 0) {
        const float4 bq4 = *reinterpret_cast<const float4*>(&bqk[col4]);
#pragma unroll
        for (int r = 0; r < 4; ++r) {
            float v0 = acc[r][0] + bq4.x, v1 = acc[r][1] + bq4.y;
            float v2 = acc[r][2] + bq4.z, v3 = acc[r][3] + bq4.w;
#pragma unroll
            for (int s = 0; s < 3; ++s) {
                const float* p = R0 + (s * 4 + r) * 260 + col4;
                v0 += p[0]; v1 += p[1]; v2 += p[2]; v3 += p[3];
            }
            sQk[r * 260 + col4 + 0] = v0; sQk[r * 260 + col4 + 1] = v1;
            sQk[r * 260 + col4 + 2] = v2; sQk[r * 260 + col4 + 3] = v3;
        }
    }
    __syncthreads();  // sQk ready, sP dead

    // ---- phase 2: wave w owns node b=w; online softmax in 8-row chunks ----
    {
        const int b = w;
        const float4 q = *reinterpret_cast<const float4*>(&sQk[b * 260 + col4]);
        const float4* f4 = reinterpret_cast<const float4*>(id2feat);
        const int* ia = sIA + b * 32;
        const int* im = sIM + b * 32;
        float4 macc = make_float4(0.f, 0.f, 0.f, 0.f);
        float4 wa = make_float4(0.f, 0.f, 0.f, 0.f);
        float m = -1e30f, e = 0.f;
#pragma unroll
        for (int cch = 0; cch < 4; ++cch) {
            float4 r[8];
#pragma unroll
            for (int j = 0; j < 8; ++j) r[j] = f4[(size_t)ia[cch * 8 + j] * 64 + l];
#pragma unroll
            for (int j = 0; j < 8; ++j) {
                const float4 v = f4[(size_t)im[cch * 8 + j] * 64 + l];
                macc.x += v.x; macc.y += v.y; macc.z += v.z; macc.w += v.w;
            }
            float p[8];
#pragma unroll
            for (int j = 0; j < 8; ++j) {
                float s = q.x * r[j].x + q.y * r[j].y + q.z * r[j].z + q.w * r[j].w;
#pragma unroll
                for (int off = 32; off; off >>= 1) s += __shfl_xor(s, off);
                p[j] = s;
            }
            float cm = p[0];
#pragma unroll
            for (int j = 1; j < 8; ++j) cm = fmaxf(cm, p[j]);
            const float newm = fmaxf(m, cm);
            const float sc = __expf(m - newm);
            e *= sc; wa.x *= sc; wa.y *= sc; wa.z *= sc; wa.w *= sc;
#pragma unroll
            for (int j = 0; j < 8; ++j) {
                const float g = __expf(p[j] - newm);
                e += g;
                wa.x += g * r[j].x; wa.y += g * r[j].y;
                wa.z += g * r[j].z; wa.w += g * r[j].w;
            }
            m = newm;
        }
        const float inv = 1.0f / e;
        const float mix[4] = {wa.x * inv, wa.y * inv, wa.z * inv, wa.w * inv};
        const float mev[4] = {macc.x * (1.f / 32), macc.y * (1.f / 32),
                              macc.z * (1.f / 32), macc.w * (1.f / 32)};
        // AF transposed: mix -> cols [0,256), mean -> cols [256,512)
#pragma unroll
        for (int c = 0; c < 4; ++c) {
            R0[SAF4(col4 + c) + b] = mix[c];
            R0[SAF4(256 + col4 + c) + b] = mev[c];
        }
    }
    __syncthreads();  // sAF ready

    // ---- phase 3: K-quarter [kq*128, +128) of AF(4x512)@Wfused ----
#pragma unroll
    for (int r = 0; r < 4; ++r)
#pragma unroll
        for (int c = 0; c < 4; ++c) acc[r][c] = 0.f;
    {
        const float* Bp = Wfused + (size_t)(kq * 128) * 256 + col4;
        float4 bufA[8], bufB[8];
#pragma unroll
        for (int j = 0; j < 8; ++j)
            bufA[j] = *reinterpret_cast<const float4*>(&Bp[(size_t)j * 256]);
        for (int kb = 0; kb < 128; kb += 16) {
#pragma unroll
            for (int j = 0; j < 8; ++j)
                bufB[j] = *reinterpret_cast<const float4*>(&Bp[(size_t)(kb + 8 + j) * 256]);
#pragma unroll
            for (int j = 0; j < 8; ++j) {
                const float4 a4 =
                    *reinterpret_cast<const float4*>(&R0[SAF4(kq * 128 + kb + j)]);
                FMA44(a4, bufA[j]);
            }
            if (kb + 16 < 128) {
#pragma unroll
                for (int j = 0; j < 8; ++j)
                    bufA[j] = *reinterpret_cast<const float4*>(&Bp[(size_t)(kb + 16 + j) * 256]);
            }
#pragma unroll
            for (int j = 0; j < 8; ++j) {
                const float4 a4 =
                    *reinterpret_cast<const float4*>(&R0[SAF4(kq * 128 + kb + 8 + j)]);
                FMA44(a4, bufB[j]);
            }
        }
    }
    __syncthreads();  // sAF dead
    if (kq) {
        float* p = R0 + ((kq - 1) * 4) * 260 + col4;
#pragma unroll
        for (int r = 0; r < 4; ++r) {
            p[r * 260 + 0] = acc[r][0]; p[r * 260 + 1] = acc[r][1];
            p[r * 260 + 2] = acc[r][2]; p[r * 260 + 3] = acc[r][3];
        }
    }
    __syncthreads();
    if (kq == 0) {
        const float4 bf4 = *reinterpret_cast<const float4*>(&bfull[col4]);
#pragma unroll
        for (int r = 0; r < 4; ++r) {
            float v0 = acc[r][0] + bf4.x, v1 = acc[r][1] + bf4.y;
            float v2 = acc[r][2] + bf4.z, v3 = acc[r][3] + bf4.w;
#pragma unroll
            for (int s = 0; s < 3; ++s) {
                const float* p = R0 + (s * 4 + r) * 260 + col4;
                v0 += p[0]; v1 += p[1]; v2 += p[2]; v3 += p[3];
            }
            v0 = tanhf(v0); v1 = tanhf(v1); v2 = tanhf(v2); v3 = tanhf(v3);
            float sq = v0 * v0 + v1 * v1 + v2 * v2 + v3 * v3;
#pragma unroll
            for (int off = 32; off; off >>= 1) sq += __shfl_xor(sq, off);
            const float invn = 1.0f / fmaxf(sqrtf(sq), 1e-12f);
            *reinterpret_cast<float4*>(&out[(size_t)(row0 + r) * 256 + col4]) =
                make_float4(v0 * invn, v1 * invn, v2 * invn, v3 * invn);
        }
    }
}

extern "C" void kernel_launch(void* const* d_in, const int* in_sizes, int n_in,
                              void* d_out, int out_size, void* d_ws, size_t ws_size,
                              hipStream_t stream) {
    const int* nodes      = (const int*)d_in[0];
    const int* neigh_mean = (const int*)d_in[1];
    const int* neigh_attn = (const int*)d_in[2];
    const float* id2feat  = (const float*)d_in[3];
    const float* Wm = (const float*)d_in[4];
    const float* bm = (const float*)d_in[5];
    const float* Wq = (const float*)d_in[6];
    const float* bq = (const float*)d_in[7];
    const float* Wk = (const float*)d_in[8];
    // d_in[9] = bk: cancels in softmax
    const float* Wv = (const float*)d_in[10];
    const float* bv = (const float*)d_in[11];
    const float* Wc = (const float*)d_in[12];
    const float* bc = (const float*)d_in[13];
    float* out = (float*)d_out;

    const int B = in_sizes[0];  // 4096

    float* ws    = (float*)d_ws;
    float* WkT   = ws;                 // 65536
    float* Wqk   = ws + 65536;         // 65536
    float* Wvc   = ws + 131072;        // 65536 } contiguous Wfused[512][256]
    float* Wmc   = ws + 196608;        // 65536 }
    float* bqk   = ws + 262144;        // 256
    float* bfull = ws + 262400;        // 256

    transpose256<<<dim3(8, 8), dim3(32, 8), 0, stream>>>(Wk, WkT);
    precompute3<<<dim3(32, 3), 256, 0, stream>>>(Wq, Wv, Wm, Wc, WkT, Wqk, Wvc, Wmc);
    bias_k<<<256, 256, 0, stream>>>(bq, bv, bm, bc, Wc, WkT, bqk, bfull);
    fused4<<<B / 4, 256, 0, stream>>>(id2feat, nodes, neigh_mean, neigh_attn,
                                      Wqk, bqk, Wvc /*Wfused*/, bfull, out);
}

// Round 9
// 88.749 us; speedup vs baseline: 1.7478x; 1.7478x over previous
//
#include <hip/hip_runtime.h>
#include <math.h>

#define S_NEI 32

// ---------------- transpose 256x256 (WkT[e][f] = Wk[f][e]) ----------------
__global__ __launch_bounds__(256) void transpose256(const float* __restrict__ in,
                                                    float* __restrict__ outT) {
    __shared__ float tile[32][33];
    const int bx = blockIdx.x * 32, by = blockIdx.y * 32;
    const int x = threadIdx.x, y = threadIdx.y;  // 32 x 8
#pragma unroll
    for (int i = 0; i < 32; i += 8)
        tile[y + i][x] = in[(by + y + i) * 256 + bx + x];
    __syncthreads();
#pragma unroll
    for (int i = 0; i < 32; i += 8)
        outT[(bx + y + i) * 256 + by + x] = tile[x][y + i];
}

// ---------------- legacy 8x256 tile GEMM (for tiny precompute GEMMs) -------
template <int KT>
__device__ __forceinline__ void gemm_tile8(const float* __restrict__ A, int row0,
                                           const float* __restrict__ B,
                                           float acc[2][4], float* __restrict__ sA,
                                           float* __restrict__ sB) {
    const int t = threadIdx.x;
    const int tr = t >> 6, tc = t & 63;
    const int r = t >> 5;
    const int k1 = t & 31;
    const size_t arow = (size_t)(row0 + r) * KT;
    for (int kb = 0; kb < KT; kb += 32) {
        sA[k1 * 12 + r] = A[arow + kb + k1];
#pragma unroll
        for (int i = 0; i < 8; ++i) {
            *reinterpret_cast<float4*>(&sB[(i * 4 + tr) * 256 + tc * 4]) =
                *reinterpret_cast<const float4*>(&B[(size_t)(kb + i * 4 + tr) * 256 + tc * 4]);
        }
        __syncthreads();
#pragma unroll
        for (int k = 0; k < 32; ++k) {
            const float2 a2 = *reinterpret_cast<const float2*>(&sA[k * 12 + tr * 2]);
            const float4 b4 = *reinterpret_cast<const float4*>(&sB[k * 256 + tc * 4]);
            acc[0][0] += a2.x * b4.x; acc[0][1] += a2.x * b4.y;
            acc[0][2] += a2.x * b4.z; acc[0][3] += a2.x * b4.w;
            acc[1][0] += a2.y * b4.x; acc[1][1] += a2.y * b4.y;
            acc[1][2] += a2.y * b4.z; acc[1][3] += a2.y * b4.w;
        }
        __syncthreads();
    }
}

// Wqk=Wq@WkT, Wvc=Wv@Wc_top, Wmc=Wm@Wc_bot
__global__ __launch_bounds__(256) void precompute3(const float* __restrict__ Wq,
                                                   const float* __restrict__ Wv,
                                                   const float* __restrict__ Wm,
                                                   const float* __restrict__ Wc,
                                                   const float* __restrict__ WkT,
                                                   float* __restrict__ Wqk,
                                                   float* __restrict__ Wvc,
                                                   float* __restrict__ Wmc) {
    __shared__ float sA[32 * 12];
    __shared__ float sB[32 * 256];
    float acc[2][4] = {};
    const float *Ap, *Bp;
    float* Cp;
    switch (blockIdx.y) {
        case 0: Ap = Wq; Bp = WkT; Cp = Wqk; break;
        case 1: Ap = Wv; Bp = Wc; Cp = Wvc; break;
        default: Ap = Wm; Bp = Wc + 256 * 256; Cp = Wmc; break;
    }
    const int row0 = blockIdx.x * 8;
    gemm_tile8<256>(Ap, row0, Bp, acc, sA, sB);
    const int tr = threadIdx.x >> 6, tc = threadIdx.x & 63;
#pragma unroll
    for (int i = 0; i < 2; ++i) {
        float4 v = make_float4(acc[i][0], acc[i][1], acc[i][2], acc[i][3]);
        *reinterpret_cast<float4*>(&Cp[(row0 + tr * 2 + i) * 256 + tc * 4]) = v;
    }
}

// bqk = bq@WkT ; bfull = bv@Wc_top + bm@Wc_bot + bc  (block per column)
__global__ __launch_bounds__(256) void bias_k(const float* __restrict__ bq,
                                              const float* __restrict__ bv,
                                              const float* __restrict__ bm,
                                              const float* __restrict__ bc,
                                              const float* __restrict__ Wc,
                                              const float* __restrict__ WkT,
                                              float* __restrict__ bqk,
                                              float* __restrict__ bfull) {
    const int c = blockIdx.x;
    const int e = threadIdx.x;
    const int w = e >> 6, l = e & 63;
    float a = bq[e] * WkT[e * 256 + c];
    float v = bv[e] * Wc[e * 256 + c] + bm[e] * Wc[(256 + e) * 256 + c];
    __shared__ float redA[4], redV[4];
#pragma unroll
    for (int off = 32; off; off >>= 1) { a += __shfl_xor(a, off); v += __shfl_xor(v, off); }
    if (l == 0) { redA[w] = a; redV[w] = v; }
    __syncthreads();
    if (e == 0) {
        bqk[c] = redA[0] + redA[1] + redA[2] + redA[3];
        bfull[c] = bc[c] + redV[0] + redV[1] + redV[2] + redV[3];
    }
}

// ---------------- fused per-4-node megakernel, 256 threads, 4 waves --------
// Wave w = K-quarter. Lane owns 4 cols (float4 B-stream). acc[4 rows][4 cols].
// Phase 1: Qk = self(4x256)@Wqk + bqk
// Phase 2: attn+mean, 1 node/wave, online-softmax 8-row chunks
// Phase 3: out = normalize(tanh(AF(4x512)@Wfused + bfull))
// LDS region R0 aliased: sA -> sP -> sAF -> sP. Transposed layout
// SAF4(k) = k*4 + ((k>>3)<<2): float4 row-frags 16B-aligned + bank-spread.
// NOTE: __launch_bounds__(256, 2) — NOT min-waves 4. Empirically (R6/R7/R8)
// min-waves>=4 makes the allocator pick 64 VGPR and spill the prefetch
// buffers to scratch (FETCH +30 MB, VALUBusy halved). At (256,2) it picks
// 128 VGPR, no spill; 128 VGPR still admits 16 waves/CU = 4 blocks of 4 waves.

#define SAF4(k) ((k) * 4 + ((((k) >> 3)) << 2))

#define FMA44(a4, b4)                                                       \
    do {                                                                    \
        acc[0][0] += (a4).x * (b4).x; acc[0][1] += (a4).x * (b4).y;         \
        acc[0][2] += (a4).x * (b4).z; acc[0][3] += (a4).x * (b4).w;         \
        acc[1][0] += (a4).y * (b4).x; acc[1][1] += (a4).y * (b4).y;         \
        acc[1][2] += (a4).y * (b4).z; acc[1][3] += (a4).y * (b4).w;         \
        acc[2][0] += (a4).z * (b4).x; acc[2][1] += (a4).z * (b4).y;         \
        acc[2][2] += (a4).z * (b4).z; acc[2][3] += (a4).z * (b4).w;         \
        acc[3][0] += (a4).w * (b4).x; acc[3][1] += (a4).w * (b4).y;         \
        acc[3][2] += (a4).w * (b4).z; acc[3][3] += (a4).w * (b4).w;         \
    } while (0)

__global__ __launch_bounds__(256, 2) void fused4(const float* __restrict__ id2feat,
                                                 const int* __restrict__ nodes,
                                                 const int* __restrict__ neigh_mean,
                                                 const int* __restrict__ neigh_attn,
                                                 const float* __restrict__ Wqk,
                                                 const float* __restrict__ bqk,
                                                 const float* __restrict__ Wfused,
                                                 const float* __restrict__ bfull,
                                                 float* __restrict__ out) {
    // R0 [0, 12480 B) aliased sA/sP/sAF; sQk [12480, 16640);
    // sIA [16640,+512); sIM [17152,+512); pad to 18112.
    __shared__ __align__(16) char smem[18112];
    float* R0  = (float*)smem;               // 3120 floats
    float* sQk = (float*)(smem + 12480);     // 1040 floats
    int*   sIA = (int*)(smem + 16640);       // 128
    int*   sIM = (int*)(smem + 17152);       // 128

    const int t = threadIdx.x;   // 256
    const int w = t >> 6, l = t & 63;
    const int kq = w;
    const int col4 = l * 4;
    const int row0 = blockIdx.x * 4;

    if (t < 128) sIA[t] = neigh_attn[(size_t)row0 * S_NEI + t];
    else sIM[t - 128] = neigh_mean[(size_t)row0 * S_NEI + (t - 128)];

    // stage 4 self rows transposed: wave w reads row w coalesced (1 KB)
    {
        const float4 v = *reinterpret_cast<const float4*>(
            &id2feat[(size_t)nodes[row0 + w] * 256 + col4]);
        R0[SAF4(col4 + 0) + w] = v.x;
        R0[SAF4(col4 + 1) + w] = v.y;
        R0[SAF4(col4 + 2) + w] = v.z;
        R0[SAF4(col4 + 3) + w] = v.w;
    }
    __syncthreads();

    float acc[4][4] = {};

    // ---- phase 1: K-quarter [kq*64, +64), all 256 cols ----
    {
        const float* Bp = Wqk + (size_t)(kq * 64) * 256 + col4;
        float4 bufA[8], bufB[8];
#pragma unroll
        for (int j = 0; j < 8; ++j)
            bufA[j] = *reinterpret_cast<const float4*>(&Bp[(size_t)j * 256]);
        for (int kb = 0; kb < 64; kb += 16) {
#pragma unroll
            for (int j = 0; j < 8; ++j)
                bufB[j] = *reinterpret_cast<const float4*>(&Bp[(size_t)(kb + 8 + j) * 256]);
#pragma unroll
            for (int j = 0; j < 8; ++j) {
                const float4 a4 = *reinterpret_cast<const float4*>(&R0[SAF4(kq * 64 + kb + j)]);
                FMA44(a4, bufA[j]);
            }
            if (kb + 16 < 64) {
#pragma unroll
                for (int j = 0; j < 8; ++j)
                    bufA[j] = *reinterpret_cast<const float4*>(&Bp[(size_t)(kb + 16 + j) * 256]);
            }
#pragma unroll
            for (int j = 0; j < 8; ++j) {
                const float4 a4 =
                    *reinterpret_cast<const float4*>(&R0[SAF4(kq * 64 + kb + 8 + j)]);
                FMA44(a4, bufB[j]);
            }
        }
    }
    __syncthreads();  // sA dead
    if (kq) {
        float* p = R0 + ((kq - 1) * 4) * 260 + col4;
#pragma unroll
        for (int r = 0; r < 4; ++r) {
            p[r * 260 + 0] = acc[r][0]; p[r * 260 + 1] = acc[r][1];
            p[r * 260 + 2] = acc[r][2]; p[r * 260 + 3] = acc[r][3];
        }
    }
    __syncthreads();
    if (kq == 0) {
        const float4 bq4 = *reinterpret_cast<const float4*>(&bqk[col4]);
#pragma unroll
        for (int r = 0; r < 4; ++r) {
            float v0 = acc[r][0] + bq4.x, v1 = acc[r][1] + bq4.y;
            float v2 = acc[r][2] + bq4.z, v3 = acc[r][3] + bq4.w;
#pragma unroll
            for (int s = 0; s < 3; ++s) {
                const float* p = R0 + (s * 4 + r) * 260 + col4;
                v0 += p[0]; v1 += p[1]; v2 += p[2]; v3 += p[3];
            }
            sQk[r * 260 + col4 + 0] = v0; sQk[r * 260 + col4 + 1] = v1;
            sQk[r * 260 + col4 + 2] = v2; sQk[r * 260 + col4 + 3] = v3;
        }
    }
    __syncthreads();  // sQk ready, sP dead

    // ---- phase 2: wave w owns node b=w; online softmax in 8-row chunks ----
    {
        const int b = w;
        const float4 q = *reinterpret_cast<const float4*>(&sQk[b * 260 + col4]);
        const float4* f4 = reinterpret_cast<const float4*>(id2feat);
        const int* ia = sIA + b * 32;
        const int* im = sIM + b * 32;
        float4 macc = make_float4(0.f, 0.f, 0.f, 0.f);
        float4 wa = make_float4(0.f, 0.f, 0.f, 0.f);
        float m = -1e30f, e = 0.f;
#pragma unroll
        for (int cch = 0; cch < 4; ++cch) {
            float4 r[8];
#pragma unroll
            for (int j = 0; j < 8; ++j) r[j] = f4[(size_t)ia[cch * 8 + j] * 64 + l];
#pragma unroll
            for (int j = 0; j < 8; ++j) {
                const float4 v = f4[(size_t)im[cch * 8 + j] * 64 + l];
                macc.x += v.x; macc.y += v.y; macc.z += v.z; macc.w += v.w;
            }
            float p[8];
#pragma unroll
            for (int j = 0; j < 8; ++j) {
                float s = q.x * r[j].x + q.y * r[j].y + q.z * r[j].z + q.w * r[j].w;
#pragma unroll
                for (int off = 32; off; off >>= 1) s += __shfl_xor(s, off);
                p[j] = s;
            }
            float cm = p[0];
#pragma unroll
            for (int j = 1; j < 8; ++j) cm = fmaxf(cm, p[j]);
            const float newm = fmaxf(m, cm);
            const float sc = __expf(m - newm);
            e *= sc; wa.x *= sc; wa.y *= sc; wa.z *= sc; wa.w *= sc;
#pragma unroll
            for (int j = 0; j < 8; ++j) {
                const float g = __expf(p[j] - newm);
                e += g;
                wa.x += g * r[j].x; wa.y += g * r[j].y;
                wa.z += g * r[j].z; wa.w += g * r[j].w;
            }
            m = newm;
        }
        const float inv = 1.0f / e;
        const float mix[4] = {wa.x * inv, wa.y * inv, wa.z * inv, wa.w * inv};
        const float mev[4] = {macc.x * (1.f / 32), macc.y * (1.f / 32),
                              macc.z * (1.f / 32), macc.w * (1.f / 32)};
        // AF transposed: mix -> cols [0,256), mean -> cols [256,512)
#pragma unroll
        for (int c = 0; c < 4; ++c) {
            R0[SAF4(col4 + c) + b] = mix[c];
            R0[SAF4(256 + col4 + c) + b] = mev[c];
        }
    }
    __syncthreads();  // sAF ready

    // ---- phase 3: K-quarter [kq*128, +128) of AF(4x512)@Wfused ----
#pragma unroll
    for (int r = 0; r < 4; ++r)
#pragma unroll
        for (int c = 0; c < 4; ++c) acc[r][c] = 0.f;
    {
        const float* Bp = Wfused + (size_t)(kq * 128) * 256 + col4;
        float4 bufA[8], bufB[8];
#pragma unroll
        for (int j = 0; j < 8; ++j)
            bufA[j] = *reinterpret_cast<const float4*>(&Bp[(size_t)j * 256]);
        for (int kb = 0; kb < 128; kb += 16) {
#pragma unroll
            for (int j = 0; j < 8; ++j)
                bufB[j] = *reinterpret_cast<const float4*>(&Bp[(size_t)(kb + 8 + j) * 256]);
#pragma unroll
            for (int j = 0; j < 8; ++j) {
                const float4 a4 =
                    *reinterpret_cast<const float4*>(&R0[SAF4(kq * 128 + kb + j)]);
                FMA44(a4, bufA[j]);
            }
            if (kb + 16 < 128) {
#pragma unroll
                for (int j = 0; j < 8; ++j)
                    bufA[j] = *reinterpret_cast<const float4*>(&Bp[(size_t)(kb + 16 + j) * 256]);
            }
#pragma unroll
            for (int j = 0; j < 8; ++j) {
                const float4 a4 =
                    *reinterpret_cast<const float4*>(&R0[SAF4(kq * 128 + kb + 8 + j)]);
                FMA44(a4, bufB[j]);
            }
        }
    }
    __syncthreads();  // sAF dead
    if (kq) {
        float* p = R0 + ((kq - 1) * 4) * 260 + col4;
#pragma unroll
        for (int r = 0; r < 4; ++r) {
            p[r * 260 + 0] = acc[r][0]; p[r * 260 + 1] = acc[r][1];
            p[r * 260 + 2] = acc[r][2]; p[r * 260 + 3] = acc[r][3];
        }
    }
    __syncthreads();
    if (kq == 0) {
        const float4 bf4 = *reinterpret_cast<const float4*>(&bfull[col4]);
#pragma unroll
        for (int r = 0; r < 4; ++r) {
            float v0 = acc[r][0] + bf4.x, v1 = acc[r][1] + bf4.y;
            float v2 = acc[r][2] + bf4.z, v3 = acc[r][3] + bf4.w;
#pragma unroll
            for (int s = 0; s < 3; ++s) {
                const float* p = R0 + (s * 4 + r) * 260 + col4;
                v0 += p[0]; v1 += p[1]; v2 += p[2]; v3 += p[3];
            }
            v0 = tanhf(v0); v1 = tanhf(v1); v2 = tanhf(v2); v3 = tanhf(v3);
            float sq = v0 * v0 + v1 * v1 + v2 * v2 + v3 * v3;
#pragma unroll
            for (int off = 32; off; off >>= 1) sq += __shfl_xor(sq, off);
            const float invn = 1.0f / fmaxf(sqrtf(sq), 1e-12f);
            *reinterpret_cast<float4*>(&out[(size_t)(row0 + r) * 256 + col4]) =
                make_float4(v0 * invn, v1 * invn, v2 * invn, v3 * invn);
        }
    }
}

extern "C" void kernel_launch(void* const* d_in, const int* in_sizes, int n_in,
                              void* d_out, int out_size, void* d_ws, size_t ws_size,
                              hipStream_t stream) {
    const int* nodes      = (const int*)d_in[0];
    const int* neigh_mean = (const int*)d_in[1];
    const int* neigh_attn = (const int*)d_in[2];
    const float* id2feat  = (const float*)d_in[3];
    const float* Wm = (const float*)d_in[4];
    const float* bm = (const float*)d_in[5];
    const float* Wq = (const float*)d_in[6];
    const float* bq = (const float*)d_in[7];
    const float* Wk = (const float*)d_in[8];
    // d_in[9] = bk: cancels in softmax
    const float* Wv = (const float*)d_in[10];
    const float* bv = (const float*)d_in[11];
    const float* Wc = (const float*)d_in[12];
    const float* bc = (const float*)d_in[13];
    float* out = (float*)d_out;

    const int B = in_sizes[0];  // 4096

    float* ws    = (float*)d_ws;
    float* WkT   = ws;                 // 65536
    float* Wqk   = ws + 65536;         // 65536
    float* Wvc   = ws + 131072;        // 65536 } contiguous Wfused[512][256]
    float* Wmc   = ws + 196608;        // 65536 }
    float* bqk   = ws + 262144;        // 256
    float* bfull = ws + 262400;        // 256

    transpose256<<<dim3(8, 8), dim3(32, 8), 0, stream>>>(Wk, WkT);
    precompute3<<<dim3(32, 3), 256, 0, stream>>>(Wq, Wv, Wm, Wc, WkT, Wqk, Wvc, Wmc);
    bias_k<<<256, 256, 0, stream>>>(bq, bv, bm, bc, Wc, WkT, bqk, bfull);
    fused4<<<B / 4, 256, 0, stream>>>(id2feat, nodes, neigh_mean, neigh_attn,
                                      Wqk, bqk, Wvc /*Wfused*/, bfull, out);
}